// Round 4
// baseline (263.639 us; speedup 1.0000x reference)
//
#include <hip/hip_runtime.h>

#define DD 256
#define BB 512

// workspace layout (float offsets)
#define OFF_RS   0          // 512*256 row sums
#define OFF_CSP  131072     // 2048*256 col-sum partials (4 per batch)
#define OFF_HFC  655360     // 4 fc1 pre-activations
#define OFF_PAR  655368     // [0]=lo_bp, [1]=hi_bp, [2..11]=bp[10]
#define OFF_TABP 655384     // DELTA table: 33 rows * 8 floats (row s=0 is zeros)
#define OFF_TABO 655648     // ORIG  table: 33 rows * 8 floats

typedef float v2f __attribute__((ext_vector_type(2)));

__device__ __forceinline__ v2f mk2(float a, float b) { v2f r; r.x = a; r.y = b; return r; }

__device__ __forceinline__ v2f fma2(v2f a, v2f b, v2f c) {
#if __has_builtin(__builtin_elementwise_fma)
  return __builtin_elementwise_fma(a, b, c);   // -> v_pk_fma_f32
#else
  return mk2(fmaf(a.x, b.x, c.x), fmaf(a.y, b.y, c.y));
#endif
}

__device__ __forceinline__ float wave_red(float v) {
#pragma unroll
  for (int off = 32; off > 0; off >>= 1) v += __shfl_down(v, off, 64);
  return v;
}

__device__ __forceinline__ float rfl(float v) {   // pin wave-uniform value to SGPR
  return __uint_as_float(__builtin_amdgcn_readfirstlane(__float_as_uint(v)));
}

// ---- K1: row sums + col-sum partials; block 2048 builds PWL tables ----
__global__ __launch_bounds__(256) void sum_kernel(const float* __restrict__ x,
                                                  const float* __restrict__ w1,
                                                  const float* __restrict__ b1,
                                                  const float* __restrict__ w2,
                                                  float* __restrict__ ws) {
  const int bq = blockIdx.x;
  const int tid = threadIdx.x;
  if (bq == 2048) {                  // ---- table-builder block ----
    const int t = tid;
    float w1v[10], b1v[10], bp[10];
    int rank[10];
#pragma unroll
    for (int c = 0; c < 10; ++c) { w1v[c] = w1[c]; b1v[c] = b1[c]; bp[c] = -b1v[c] / w1v[c]; }
#pragma unroll
    for (int c = 0; c < 10; ++c) {
      int r = 0;
#pragma unroll
      for (int k = 0; k < 10; ++k)
        r += (bp[k] < bp[c] || (bp[k] == bp[c] && k < c)) ? 1 : 0;
      rank[c] = r;
    }
    float lo = bp[0], hi = bp[0];
#pragma unroll
    for (int c = 1; c < 10; ++c) { lo = fminf(lo, bp[c]); hi = fmaxf(hi, bp[c]); }
    if (t == 0) { ws[OFF_PAR] = lo; ws[OFF_PAR + 1] = hi; }
    if (t >= 16 && t < 26) ws[OFF_PAR + 2 + (t - 16)] = bp[t - 16];
    if (t < 99) {
      const int s = t / 9, tt = t % 9;    // tt = dr*3 + kc
      const int dr = tt / 3, kc = tt % 3;
      float A = 0.f, Bv = 0.f;            // orig coefficients for segment s
      for (int c = 0; c < 10; ++c) {
        bool act = (w1v[c] > 0.f) ? (rank[c] < s)
                 : ((w1v[c] < 0.f) ? (rank[c] >= s) : (b1v[c] > 0.f));
        if (act) { A += w1v[c] * w2[c * 9 + tt]; Bv += b1v[c] * w2[c * 9 + tt]; }
      }
      float A0 = 0.f, B0 = 0.f;           // s=0 (low) coefficients
      for (int c = 0; c < 10; ++c) {
        bool act0 = (w1v[c] < 0.f) || (w1v[c] == 0.f && b1v[c] > 0.f);
        if (act0) { A0 += w1v[c] * w2[c * 9 + tt]; B0 += b1v[c] * w2[c * 9 + tt]; }
      }
      const int base = (s * 3 + kc) * 8;
      const int posA = (dr == 2) ? 4 : dr;
      const int posB = (dr == 2) ? 5 : (2 + dr);
      ws[OFF_TABO + base + posA] = A;
      ws[OFF_TABO + base + posB] = Bv;
      ws[OFF_TABP + base + posA] = A - A0;
      ws[OFF_TABP + base + posB] = Bv - B0;
      ws[OFF_TABO + base + 6] = 0.f; ws[OFF_TABO + base + 7] = 0.f;
      ws[OFF_TABP + base + 6] = 0.f; ws[OFF_TABP + base + 7] = 0.f;
    }
    return;
  }
  // ---- streaming sum block (unchanged, proven) ----
  const int b = bq >> 2;
  const int q = bq & 3;
  const int lane = tid & 63;
  const int wv = tid >> 6;
  __shared__ float rowp[64][65];
  __shared__ float csl[4][DD];
  __shared__ float segp[4][64];
  float4 cacc = make_float4(0.f, 0.f, 0.f, 0.f);
  const float4* px = (const float4*)(x + ((size_t)b << 16) + ((size_t)(q * 64 + wv * 16) << 8));
#pragma unroll
  for (int r = 0; r < 16; ++r) {
    float4 val = px[r * 64 + lane];
    cacc.x += val.x; cacc.y += val.y; cacc.z += val.z; cacc.w += val.w;
    rowp[wv * 16 + r][lane] = (val.x + val.y) + (val.z + val.w);
  }
  ((float4*)csl[wv])[lane] = cacc;
  __syncthreads();
  {
    const int row = tid & 63, seg = tid >> 6;
    const float* rp = rowp[row] + seg * 16;
    float s = 0.f;
#pragma unroll
    for (int k = 0; k < 16; ++k) s += rp[k];
    segp[seg][row] = s;
  }
  __syncthreads();
  if (tid < 64)
    ws[OFF_RS + b * DD + q * 64 + tid] =
        (segp[0][tid] + segp[1][tid]) + (segp[2][tid] + segp[3][tid]);
  ws[OFF_CSP + bq * DD + tid] =
      (csl[0][tid] + csl[1][tid]) + (csl[2][tid] + csl[3][tid]);
  if (bq == 0 && tid < 4) ws[OFF_HFC + tid] = 0.f;
}

// ---- K2: 2 blocks/image x 8 waves; register two-segment fast path ----
__global__ __launch_bounds__(512, 6) void conv_kernel(const float* __restrict__ b2p,
                                                      const float* __restrict__ fc1w,
                                                      float* __restrict__ ws) {
  const int b = blockIdx.x >> 1;     // image
  const int h = blockIdx.x & 1;      // half (run group)
  const int tid = threadIdx.x;
  const int w = tid >> 6;            // wave 0..7
  const int lane = tid & 63;
  const int run = (h << 3) | w;      // 0..15 in the balanced run map

  int wb, r0, r1;
  switch (run) {
    case 0:  wb = 0; r0 = 0;   r1 = 43;  break;
    case 1:  wb = 0; r0 = 43;  r1 = 86;  break;
    case 2:  wb = 0; r0 = 86;  r1 = 129; break;
    case 3:  wb = 0; r0 = 129; r1 = 172; break;
    case 4:  wb = 0; r0 = 172; r1 = 214; break;
    case 5:  wb = 0; r0 = 214; r1 = 256; break;
    case 6:  wb = 1; r0 = 62;  r1 = 101; break;
    case 7:  wb = 1; r0 = 101; r1 = 140; break;
    case 8:  wb = 1; r0 = 140; r1 = 179; break;
    case 9:  wb = 1; r0 = 179; r1 = 218; break;
    case 10: wb = 1; r0 = 218; r1 = 256; break;
    case 11: wb = 2; r0 = 126; r1 = 170; break;
    case 12: wb = 2; r0 = 170; r1 = 213; break;
    case 13: wb = 2; r0 = 213; r1 = 256; break;
    case 14: wb = 3; r0 = 190; r1 = 223; break;
    default: wb = 3; r0 = 223; r1 = 256; break;
  }
  const int jmin = wb * 64;
  const int j = jmin + lane;
  const int dlim = jmin + 63;        // last input row with any masked lane

  __shared__ __align__(16) float tabD_s[264];
  __shared__ __align__(16) float tabO_s[264];
  __shared__ float rs_s[DD];
  __shared__ float cs_s[DD];
  __shared__ __align__(16) float wkA[DD][4];
  __shared__ float segsum_s[4][4];
  __shared__ float red_s[32];

  // ---- wave-uniform scalar params (ws is L2-hot; compiler emits s_loads) ----
  const float* par = ws + OFF_PAR;
  const float lo_s = rfl(par[0]);
  const float hi_s = rfl(par[1]);
  float bp_r[10];
#pragma unroll
  for (int c = 0; c < 10; ++c) bp_r[c] = rfl(par[2 + c]);
  float dH[3][6];                    // delta coefficients of segment s=10
  {
    const float* dhp = ws + OFF_TABP + 240;   // (10*3+0)*8
#pragma unroll
    for (int kc = 0; kc < 3; ++kc)
#pragma unroll
      for (int m = 0; m < 6; ++m) dH[kc][m] = rfl(dhp[kc * 8 + m]);
  }

  // ---- preamble ----
  if (tid < 256) {
    rs_s[tid] = ws[OFF_RS + b * DD + tid];
#pragma unroll
    for (int k = 0; k < 4; ++k) wkA[tid][k] = fc1w[k * (BB * DD) + b * DD + tid];
  } else {
    const int t = tid - 256;
    const float* csp = ws + OFF_CSP + (b * 4) * DD + t;
    cs_s[t] = (csp[0] + csp[DD]) + (csp[2 * DD] + csp[3 * DD]);
  }
  if (tid < 264) { tabD_s[tid] = ws[OFF_TABP + tid]; tabO_s[tid] = ws[OFF_TABO + tid]; }
  __syncthreads();
  if (tid < 16) {
    const int ss = tid >> 2, k = tid & 3;
    float s = 0.f;
#pragma unroll
    for (int r = 0; r < 64; ++r) s += wkA[ss * 64 + r][k];
    segsum_s[ss][k] = s;
  }
  __syncthreads();

  const float b2v = b2p[0];
  const float yb = fmaxf(b2v, 0.f);

  float csr[3], vf[3];
  csr[0] = (j >= 1) ? cs_s[j - 1] : 0.f;
  csr[1] = cs_s[j];
  csr[2] = (j < DD - 1) ? cs_s[j + 1] : 0.f;
  vf[0] = (j >= 1) ? 1.f : 0.f;
  vf[1] = 1.f;
  vf[2] = (j < DD - 1) ? 1.f : 0.f;
  v2f vf2[3];
#pragma unroll
  for (int kc = 0; kc < 3; ++kc) vf2[kc] = mk2(vf[kc], vf[kc]);

  // ---- per-lane fold of the unconditional s=0 (low) linear part ----
  v2f al01 = mk2(0.f, 0.f), be01 = mk2(0.f, 0.f);
  float al2 = 0.f, be2 = 0.f;
  {
    const float* lop = ws + OFF_TABO;       // row s=0
#pragma unroll
    for (int kc = 0; kc < 3; ++kc) {
      const float A0 = rfl(lop[kc * 8 + 0]), A1 = rfl(lop[kc * 8 + 1]);
      const float B0 = rfl(lop[kc * 8 + 2]), B1 = rfl(lop[kc * 8 + 3]);
      const float A2 = rfl(lop[kc * 8 + 4]), B2 = rfl(lop[kc * 8 + 5]);
      const v2f a = mk2(A0, A1);
      al01 = fma2(vf2[kc], a, al01);
      be01 = fma2(vf2[kc], fma2(a, mk2(csr[kc], csr[kc]), mk2(B0, B1)), be01);
      al2 = fmaf(vf[kc], A2, al2);
      be2 = fmaf(vf[kc], fmaf(A2, csr[kc], B2), be2);
    }
  }

  const int iend = (r1 == DD) ? DD - 1 : r1;
  float P = 0.f, Q = 0.f;
  float vcol = 0.f;
  v2f a01 = mk2(0.f, 0.f);
  v2f a23 = mk2(0.f, 0.f);

  // fast eval: all taps in-tril; two-segment register path + rare LDS fixup
  auto fast_eval = [&](float rsv, v2f& R01, float& R2) {
    R01 = fma2(al01, mk2(rsv, rsv), be01);
    R2 = fmaf(al2, rsv, be2);
    int ia = 0;
#pragma unroll
    for (int kc = 0; kc < 3; ++kc) {
      const float e = rsv + csr[kc];
      const bool hib = e > hi_s;
      const v2f tv = fma2(mk2(e, e), mk2(dH[kc][0], dH[kc][1]), mk2(dH[kc][2], dH[kc][3]));
      const v2f mh2 = hib ? vf2[kc] : mk2(0.f, 0.f);
      R01 = fma2(mh2, tv, R01);
      const float t2 = fmaf(e, dH[kc][4], dH[kc][5]);
      R2 = fmaf(hib ? vf[kc] : 0.f, t2, R2);
      ia |= (!hib && (e > lo_s)) ? 1 : 0;
    }
    if (__any(ia)) {                 // rare interior lanes: exact segment via cmps
#pragma unroll
      for (int kc = 0; kc < 3; ++kc) {
        const float e = rsv + csr[kc];
        if ((e > lo_s) && (e <= hi_s)) {
          int s = 0;
#pragma unroll
          for (int c = 0; c < 10; ++c) s += (bp_r[c] < e) ? 1 : 0;
          const char* tp = (const char*)tabD_s + s * 96 + kc * 32;
          const float4 ab = *(const float4*)tp;
          const float2 ab2 = *(const float2*)(tp + 16);
          const v2f tv = fma2(mk2(ab.x, ab.y), mk2(e, e), mk2(ab.z, ab.w));
          R01 = fma2(vf2[kc], tv, R01);
          R2 = fmaf(vf[kc], fmaf(ab2.x, e, ab2.y), R2);
        }
      }
    }
  };

  // guarded eval: per-tap tril mask, full orig-table path (exact segment via cmps)
  auto guard_eval = [&](float rsv, int i, v2f& R01, float& R2) {
#pragma unroll
    for (int kc = 0; kc < 3; ++kc) {
      const float e = rsv + csr[kc];
      const float m = ((j - 1 + kc) <= i) ? vf[kc] : 0.f;
      int s = 0;
#pragma unroll
      for (int c = 0; c < 10; ++c) s += (bp_r[c] < e) ? 1 : 0;
      const char* tp = (const char*)tabO_s + s * 96 + kc * 32;
      const float4 ab = *(const float4*)tp;
      const float2 ab2 = *(const float2*)(tp + 16);
      const v2f tv = fma2(mk2(ab.x, ab.y), mk2(e, e), mk2(ab.z, ab.w));
      R01 = fma2(mk2(m, m), tv, R01);
      R2 = fmaf(m, fmaf(ab2.x, e, ab2.y), R2);
    }
  };

  auto finalize = [&](int i, float R2v) {
    const float yd = fmaxf(P + R2v + b2v, 0.f) - yb;
    vcol += yd;
    const float4 wkv = *(const float4*)wkA[i - 1];
    a01 = fma2(mk2(yd, yd), mk2(wkv.x, wkv.y), a01);
    a23 = fma2(mk2(yd, yd), mk2(wkv.z, wkv.w), a23);
  };

  if (r0 >= dlim + 2) {
    // ---- interior-class run: 2 fast warmups (no finalize), then fast loop ----
    for (int i = r0 - 1; i <= r0; ++i) {
      v2f R01; float R2;
      fast_eval(rs_s[i], R01, R2);
      P = Q + R01.y; Q = R01.x;
    }
    for (int i = r0 + 1; i <= iend; ++i) {
      v2f R01; float R2;
      fast_eval(rs_s[i], R01, R2);
      finalize(i, R2);
      P = Q + R01.y; Q = R01.x;
    }
  } else {
    // ---- diagonal-class run: guarded phase, then unmasked fast continuation ----
    const int ibeg = (r0 == 0) ? 0 : r0 - 1;
    const int ffrom = r0 + 1;
    const int gend = (iend < dlim) ? iend : dlim;
    for (int i = ibeg; i <= gend; ++i) {
      v2f R01 = mk2(0.f, 0.f); float R2 = 0.f;
      if (j - 1 <= i) guard_eval(rs_s[i], i, R01, R2);
      if (i >= ffrom) finalize(i, R2);
      P = Q + R01.y; Q = R01.x;
    }
    for (int i = dlim + 1; i <= iend; ++i) {
      v2f R01; float R2;
      fast_eval(rs_s[i], R01, R2);
      finalize(i, R2);
      P = Q + R01.y; Q = R01.x;
    }
  }
  if (r1 == DD) {                    // flush output row 255
    const float yd = fmaxf(P + b2v, 0.f) - yb;
    vcol += yd;
    const float4 wkv = *(const float4*)wkA[DD - 1];
    a01 = fma2(mk2(yd, yd), mk2(wkv.x, wkv.y), a01);
    a23 = fma2(mk2(yd, yd), mk2(wkv.z, wkv.w), a23);
  }

  // column-sum term: vcol * Wk[b, j]
  const float4 wkj = *(const float4*)wkA[j];
  a01 = fma2(mk2(vcol, vcol), mk2(wkj.x, wkj.y), a01);
  a23 = fma2(mk2(vcol, vcol), mk2(wkj.z, wkj.w), a23);

  float acc0 = wave_red(a01.x), acc1 = wave_red(a01.y);
  float acc2 = wave_red(a23.x), acc3 = wave_red(a23.y);
  if (lane == 0) {
    red_s[w * 4 + 0] = acc0; red_s[w * 4 + 1] = acc1;
    red_s[w * 4 + 2] = acc2; red_s[w * 4 + 3] = acc3;
  }
  __syncthreads();
  if (tid < 4) {
    float s = 0.f;
#pragma unroll
    for (int wv = 0; wv < 8; ++wv) s += red_s[wv * 4 + tid];
    // closed-form yb baseline, half per block: 256*yb*sum_r wk[r]
    const float wt = (segsum_s[0][tid] + segsum_s[1][tid]) +
                     (segsum_s[2][tid] + segsum_s[3][tid]);
    s = fmaf(256.f * yb, wt, s);
    atomicAdd(&ws[OFF_HFC + tid], s);
  }
}

// ---- K3: relu(fc1) -> fc2 -> 2 outputs ----
__global__ void fc_kernel(const float* __restrict__ fc1b, const float* __restrict__ fc2w,
                          const float* __restrict__ fc2b, const float* __restrict__ ws,
                          float* __restrict__ out) {
  if (threadIdx.x == 0 && blockIdx.x == 0) {
    float o0 = fc2b[0], o1 = fc2b[1];
#pragma unroll
    for (int k = 0; k < 4; ++k) {
      float h = fmaxf(ws[OFF_HFC + k] + fc1b[k], 0.f);
      o0 += fc2w[k] * h;
      o1 += fc2w[4 + k] * h;
    }
    out[0] = o0; out[1] = o1;
  }
}

extern "C" void kernel_launch(void* const* d_in, const int* in_sizes, int n_in,
                              void* d_out, int out_size, void* d_ws, size_t ws_size,
                              hipStream_t stream) {
  const float* x    = (const float*)d_in[0];
  const float* w1   = (const float*)d_in[1];
  const float* b1   = (const float*)d_in[2];
  const float* w2   = (const float*)d_in[3];
  const float* b2   = (const float*)d_in[4];
  const float* fc1w = (const float*)d_in[5];
  const float* fc1b = (const float*)d_in[6];
  const float* fc2w = (const float*)d_in[7];
  const float* fc2b = (const float*)d_in[8];
  float* out = (float*)d_out;
  float* ws  = (float*)d_ws;

  hipLaunchKernelGGL(sum_kernel,  dim3(2049), dim3(256), 0, stream, x, w1, b1, w2, ws);
  hipLaunchKernelGGL(conv_kernel, dim3(1024), dim3(512), 0, stream, b2, fc1w, ws);
  hipLaunchKernelGGL(fc_kernel,   dim3(1), dim3(64), 0, stream, fc1b, fc2w, fc2b, ws, out);
}